// Round 3
// baseline (242.914 us; speedup 1.0000x reference)
//
#include <hip/hip_runtime.h>
#include <hip/hip_bf16.h>
#include <math.h>

typedef unsigned short u16;

#define BATCH 16384
#define HID   512
#define KDIM  1024   // INPUT + HIDDEN
#define BM    128    // batch rows per block
#define NSTEP 16     // K-steps of 64

typedef __bf16 bf16x8 __attribute__((ext_vector_type(8)));
typedef float  floatx4 __attribute__((ext_vector_type(4)));

__device__ __forceinline__ float fast_sigmoid(float x) {
  return 1.0f / (1.0f + __expf(-x));
}
__device__ __forceinline__ float fast_tanh(float x) {
  float e = __expf(-2.0f * fabsf(x));
  float t = (1.0f - e) / (1.0f + e);
  return x >= 0.0f ? t : -t;
}
__device__ __forceinline__ u16 f2bf(float f) {
  return __builtin_bit_cast(u16, __float2bfloat16(f));
}

// Raw barrier: only LDS ordering is needed at the step boundary (bf16 tile
// ds_writes -> other waves' ds_reads). Global loads land in registers or in
// per-wave-private ring slots; they are ordered by counted vmcnt, NOT drained
// here (T4: never vmcnt(0) in the main loop).
__device__ __forceinline__ void barrier_lds_only() {
  asm volatile("s_waitcnt lgkmcnt(0)" ::: "memory");
  __builtin_amdgcn_s_barrier();
  __builtin_amdgcn_sched_barrier(0);
}

// ---------- pre-pass: W only ----------
// Wf: MFMA-FRAGMENT-MAJOR weights so B-loads are one coalesced dwordx4:
//   elem (gate g, per-gate col n, k) lives at
//   (((g*32 + n/16)*32 + k/32)*64 + ((k>>3)&3)*16 + (n&15))*8 + (k&7)
__global__ __launch_bounds__(256) void pack_w_kernel(
    const float* __restrict__ Wi, const float* __restrict__ Wf_,
    const float* __restrict__ Wo, const float* __restrict__ Wg,
    u16* __restrict__ Wf) {
  int grow = blockIdx.x;                  // 0..2047, order [Wi|Wf|Wo|Wg]
  int k = threadIdx.x * 4;
  int g = grow >> 9;
  int n = grow & (HID - 1);
  const float* s = g == 0 ? Wi : g == 1 ? Wf_ : g == 2 ? Wo : Wg;
  float4 v = *(const float4*)(s + (size_t)n * KDIM + k);
  ushort4 o;
  o.x = f2bf(v.x); o.y = f2bf(v.y); o.z = f2bf(v.z); o.w = f2bf(v.w);
  size_t d = ((size_t)((g * 32 + (n >> 4)) * 32 + (k >> 5)) * 64 +
              ((k >> 3) & 3) * 16 + (n & 15)) * 8 + (k & 7);
  *(ushort4*)(Wf + d) = o;
}

// ---------- main fused GEMM + LSTM epilogue ----------
// X pipeline (3-deep, LDS ring):
//   iter S: compute(bf16[S&1])               <- ds_read, MFMA
//           loadB(S+1) (registers, L2)        <- in flight across barrier
//           fetchX(S+2) -> ring[(S+2)%3]      <- global_load_lds fp32, 2-iter cover
//           vmcnt(12)  [fetchX(S+1) done; 12 newer ops outstanding]
//           cvt ring[(S+1)%3] -> bf16[(S+1)&1]  (fp32->bf16, swizzled write)
//           lgkmcnt(0); s_barrier
// Ring slots are PER-WAVE-PRIVATE (each wave fetches + converts its own 16
// rows): no cross-wave hazard on the ring; slot reuse distance = 2 iters,
// ds_reads of the old slot retired at the prior barrier's lgkmcnt(0).
// Ring swizzle (16B chunks): phys = ch ^ ((row&7)<<1), applied on the GLOBAL
// source address (global_load_lds writes lane-linear). Pair-preserving (even
// XOR) so fp32 chunk pairs {2p,2p+1} stay adjacent -> cvt reads 2x b128.
// bf16 tile layout unchanged (verified): LDS[row][c^(row&7) chunk] = X chunk c.
__global__ __launch_bounds__(512, 2) void lstm_gemm_kernel(
    const float* __restrict__ input_, const float* __restrict__ prev_h,
    const u16* __restrict__ Wf,
    const float* __restrict__ Bi, const float* __restrict__ Bf,
    const float* __restrict__ Bo, const float* __restrict__ Bg,
    const float* __restrict__ prevC, float* __restrict__ out) {
  __shared__ u16   lbf[2][8192];    // bf16 A tiles (32 KB), swizzled
  __shared__ float lring[3][8192];  // fp32 X ring (96 KB): [wave 4KB][16 rows][16 chunks]

  const int tid = threadIdx.x;
  const int wave = tid >> 6, lane = tid & 63;
  const int lrow = lane & 15, lquad = lane >> 4;
  const int m_block = blockIdx.y * BM;
  const int ntg = blockIdx.x * 8 + wave;   // global per-gate 16-col tile id

  // fetch geometry: instr i covers rows wave*16 + i*4 + (lane>>4); lane's
  // 16B phys chunk = lane&15; global chunk = phys ^ ((rowloc&7)<<1).
  int goff[4];
#pragma unroll
  for (int i = 0; i < 4; ++i) {
    int rl = i * 4 + (lane >> 4);                 // row within wave region
    int gch = (lane & 15) ^ ((rl & 7) << 1);      // global 16B chunk
    goff[i] = (m_block + wave * 16 + rl) * HID + gch * 4;   // in floats
  }

  floatx4 acc[4][8];   // [gate][m-tile]  (AGPRs)
#pragma unroll
  for (int g = 0; g < 4; ++g)
#pragma unroll
    for (int mt = 0; mt < 8; ++mt)
      acc[g][mt] = (floatx4){0.f, 0.f, 0.f, 0.f};

  auto fetchX = [&](int S, int slot) {
    const float* src = (S < 8) ? prev_h : input_;
    int colo = (S & 7) * 64;
#pragma unroll
    for (int i = 0; i < 4; ++i) {
      const float* g = src + goff[i] + colo;                  // per-lane src
      char* l = (char*)&lring[slot][0] + wave * 4096 + i * 1024;  // uniform
      __builtin_amdgcn_global_load_lds(
          (const __attribute__((address_space(1))) void*)g,
          (__attribute__((address_space(3))) void*)l, 16, 0, 0);
    }
  };

  // cvt: lane owns ring row (lane&15) of its wave; pairs p = lquad, lquad+4.
  // reads fp32 phys chunks (2p)^xx, (2p+1)^xx (2-way bank alias = free);
  // writes bf16 chunk p at phys p^(row&7) (uniform 8/quad, conflict-free).
  auto cvt = [&](int slot, int buf) {
    const int xx = (lane & 7) << 1;
#pragma unroll
    for (int pi = 0; pi < 2; ++pi) {
      int p = lquad + pi * 4;
      const float* rp = &lring[slot][wave * 1024 + lrow * 64 + (((2 * p) ^ xx) << 2)];
      float4 v0 = *(const float4*)rp;
      float4 v1 = *(const float4*)(rp + 4);
      union { u16 u[8]; bf16x8 v; } t;
      t.u[0] = f2bf(v0.x); t.u[1] = f2bf(v0.y);
      t.u[2] = f2bf(v0.z); t.u[3] = f2bf(v0.w);
      t.u[4] = f2bf(v1.x); t.u[5] = f2bf(v1.y);
      t.u[6] = f2bf(v1.z); t.u[7] = f2bf(v1.w);
      *(bf16x8*)&lbf[buf][(wave * 16 + lrow) * 64 + ((p ^ (lane & 7)) << 3)] = t.v;
    }
  };

  bf16x8 b[2][4];      // single B buffer (32 VGPRs)
  auto loadB = [&](int S) {
#pragma unroll
    for (int kk = 0; kk < 2; ++kk)
#pragma unroll
      for (int g = 0; g < 4; ++g)
        b[kk][g] = *(const bf16x8*)(
            Wf + (((size_t)(g * 32 + ntg) * 32 + (S * 2 + kk)) << 9) +
            lane * 8);
  };

  auto compute = [&](int buf) {
    const u16* LA = &lbf[buf][0];
    __builtin_amdgcn_s_setprio(1);
#pragma unroll
    for (int kk = 0; kk < 2; ++kk) {
#pragma unroll
      for (int mt = 0; mt < 8; ++mt) {
        bf16x8 a = *(const bf16x8*)
            &LA[(mt * 16 + lrow) * 64 + (((kk * 4 + lquad) ^ (lrow & 7)) * 8)];
#pragma unroll
        for (int g = 0; g < 4; ++g)
          acc[g][mt] = __builtin_amdgcn_mfma_f32_16x16x32_bf16(
              a, b[kk][g], acc[g][mt], 0, 0, 0);
      }
    }
    __builtin_amdgcn_s_setprio(0);
  };

  // ---- prologue ----
  fetchX(0, 0);
  fetchX(1, 1);
  loadB(0);
  // fetchX(0) done: 12 newer outstanding (fetchX(1)=4 + loadB(0)=8)
  asm volatile("s_waitcnt vmcnt(12)" ::: "memory");
  __builtin_amdgcn_sched_barrier(0);
  cvt(0, 0);
  barrier_lds_only();

  // ---- main loop ----
#pragma unroll
  for (int S = 0; S < NSTEP; ++S) {
    compute(S & 1);                       // b-wait: vmcnt(4) (fetchX(S+1) newer)
    if (S + 1 < NSTEP) {
      loadB(S + 1);                       // after b's last use (WAR ok)
      if (S + 2 < NSTEP) {
        fetchX(S + 2, (S + 2) % 3);
        // fetchX(S+1) done: newer = loadB(S+1)[8] + fetchX(S+2)[4]
        asm volatile("s_waitcnt vmcnt(12)" ::: "memory");
      } else {
        // S==14: newer = loadB(15)[8] only
        asm volatile("s_waitcnt vmcnt(8)" ::: "memory");
      }
      __builtin_amdgcn_sched_barrier(0);
      cvt((S + 1) % 3, (S + 1) & 1);
      barrier_lds_only();
    }
  }

  // ---- epilogue. C layout (verified): col=lane&15, row=lquad*4+reg ----
  const int j = ntg * 16 + lrow;        // 0..511
  const float vbi = Bi[j], vbf = Bf[j], vbo = Bo[j], vbg = Bg[j];
  float* outH = out;
  float* outC = out + (size_t)BATCH * HID;
#pragma unroll
  for (int mt = 0; mt < 8; ++mt) {
    int rowb = m_block + mt * 16 + lquad * 4;
#pragma unroll
    for (int rg = 0; rg < 4; ++rg) {
      int row = rowb + rg;
      float gi = fast_sigmoid(acc[0][mt][rg] + vbi);
      float gf = fast_sigmoid(acc[1][mt][rg] + vbf);
      float go = fast_sigmoid(acc[2][mt][rg] + vbo);
      float gg = fast_tanh(acc[3][mt][rg] + vbg);
      float c = gf * prevC[row * HID + j] + gi * gg;
      float h = fast_tanh(c) * go;
      outH[row * HID + j] = h;
      outC[row * HID + j] = c;
    }
  }
}

// ---------- slow fallback if ws too small (correctness insurance) ----------
__global__ void lstm_fallback_kernel(
    const float* __restrict__ input_, const float* __restrict__ prev_h,
    const float* __restrict__ prevC,
    const float* __restrict__ Wi, const float* __restrict__ Bi,
    const float* __restrict__ Wf, const float* __restrict__ Bf,
    const float* __restrict__ Wo, const float* __restrict__ Bo,
    const float* __restrict__ Wg, const float* __restrict__ Bg,
    float* __restrict__ out) {
  int idx = blockIdx.x * blockDim.x + threadIdx.x;
  int b = idx / HID, j = idx % HID;
  if (b >= BATCH) return;
  float si = 0.f, sf = 0.f, so = 0.f, sg = 0.f;
  for (int k = 0; k < KDIM; ++k) {
    float x = (k < HID) ? prev_h[b * HID + k] : input_[b * HID + (k - HID)];
    si += x * Wi[j * KDIM + k];
    sf += x * Wf[j * KDIM + k];
    so += x * Wo[j * KDIM + k];
    sg += x * Wg[j * KDIM + k];
  }
  float gi = fast_sigmoid(si + Bi[j]);
  float gf = fast_sigmoid(sf + Bf[j]);
  float go = fast_sigmoid(so + Bo[j]);
  float gg = fast_tanh(sg + Bg[j]);
  float c = gf * prevC[b * HID + j] + gi * gg;
  out[b * HID + j] = fast_tanh(c) * go;
  out[(size_t)BATCH * HID + b * HID + j] = c;
}

extern "C" void kernel_launch(void* const* d_in, const int* in_sizes, int n_in,
                              void* d_out, int out_size, void* d_ws, size_t ws_size,
                              hipStream_t stream) {
  const float* input_ = (const float*)d_in[0];
  const float* prev_h = (const float*)d_in[1];
  const float* prev_c = (const float*)d_in[2];
  const float* W_i = (const float*)d_in[3];
  const float* b_i = (const float*)d_in[4];
  const float* W_f = (const float*)d_in[5];
  const float* b_f = (const float*)d_in[6];
  const float* W_g = (const float*)d_in[7];
  const float* b_g = (const float*)d_in[8];
  const float* W_o = (const float*)d_in[9];
  const float* b_o = (const float*)d_in[10];
  float* out = (float*)d_out;

  const size_t ws_needed = (size_t)4 * HID * KDIM * sizeof(u16);   // 4 MB

  if (ws_size < ws_needed) {
    int total = BATCH * HID;
    lstm_fallback_kernel<<<(total + 255) / 256, 256, 0, stream>>>(
        input_, prev_h, prev_c, W_i, b_i, W_f, b_f, W_o, b_o, W_g, b_g, out);
    return;
  }

  u16* Wfp = (u16*)d_ws;                      // fragment-major bf16 W, 4 MB

  pack_w_kernel<<<4 * HID, 256, 0, stream>>>(W_i, W_f, W_o, W_g, Wfp);

  // x = n-block, y = m-block: the 4 blocks sharing an X slab are adjacent in
  // dispatch order -> co-resident, L2/L3 dedup the fp32 X fetch.
  dim3 grid(HID / 128, BATCH / BM);           // 4 x 128 = 512 blocks
  lstm_gemm_kernel<<<grid, 512, 0, stream>>>(input_, prev_h, Wfp,
                                             b_i, b_f, b_o, b_g, prev_c, out);
}